// Round 10
// baseline (440.723 us; speedup 1.0000x reference)
//
#include <hip/hip_runtime.h>
#include <hip/hip_bf16.h>
#include <math.h>

// ---------------------------------------------------------------------------
// DDiTBlockCausal: B=2, S=2048, D=1024, H=16, Dh=64, MLP=4096, fp32 I/O.
// Round 17:
//  - gemm64_bt: A operand moved out of LDS entirely. A-fragments (16 B/lane,
//    stride-K) load global->VGPR, double-buffered ping/pong (unroll-by-2,
//    static indexing). LDS per iter 88 -> 48 KB (B-read 32 + B-write 16):
//    R15/R16 showed this kernel is LDS-port-bound (~37 us of port time).
//    vmcnt re-derived: prologue order [A0][stage0][stage1]; per iter
//    [wait vmcnt(6) | 2@it0 | 4@last][barrier][loadA it+1][stageB it+2]
//    [B ds_read + MFMA]. sched_barrier(0) pins A-before-stage issue order
//    so counted waits stay valid. __launch_bounds__(512,4) caps VGPR at 128
//    (4 waves/SIMD preserved).
//  - everything else byte-identical to R16 (verified passing).
// ---------------------------------------------------------------------------

#define B_ 2
#define S_ 2048
#define D_ 1024
#define H_ 16
#define DH_ 64
#define MLP_ 4096
#define ROWS_ (B_ * S_)   // 4096

typedef short bf16x8 __attribute__((ext_vector_type(8)));
typedef float f32x4 __attribute__((ext_vector_type(4)));
typedef unsigned short ushort_t;
typedef ushort_t u16x4 __attribute__((ext_vector_type(4)));
typedef unsigned int u32x2 __attribute__((ext_vector_type(2)));

__device__ __forceinline__ float wave_reduce_sum(float v) {
  #pragma unroll
  for (int off = 32; off > 0; off >>= 1) v += __shfl_down(v, off, 64);
  return v;
}

__device__ __forceinline__ ushort_t f2bf(float v) {
  __hip_bfloat16 h = __float2bfloat16(v);
  return *(ushort_t*)&h;
}
__device__ __forceinline__ float bf2f(ushort_t u) {
  unsigned int v = ((unsigned int)u) << 16;
  union { unsigned int i; float f; } c; c.i = v; return c.f;
}

__device__ __forceinline__ float exp2_fast(float x) {
#if __has_builtin(__builtin_amdgcn_exp2f)
  return __builtin_amdgcn_exp2f(x);
#else
  return exp2f(x);
#endif
}
__device__ __forceinline__ float rcp_fast(float x) {
#if __has_builtin(__builtin_amdgcn_rcpf)
  return __builtin_amdgcn_rcpf(x);
#else
  return 1.0f / x;
#endif
}

__device__ __forceinline__ void async_copy16(const void* g, void* l) {
  __builtin_amdgcn_global_load_lds(
      (const __attribute__((address_space(1))) void*)g,
      (__attribute__((address_space(3))) void*)l, 16, 0, 0);
}

// ---------------- weight cast fp32 -> bf16 (4 tensors, blockIdx.y picks) ---
__global__ __launch_bounds__(256) void cast_w_kernel(
    const float* __restrict__ s0, ushort_t* __restrict__ d0, int n0,
    const float* __restrict__ s1, ushort_t* __restrict__ d1, int n1,
    const float* __restrict__ s2, ushort_t* __restrict__ d2, int n2,
    const float* __restrict__ s3, ushort_t* __restrict__ d3, int n3) {
  const float* s; ushort_t* d; int n;
  switch (blockIdx.y) {
    case 0: s = s0; d = d0; n = n0; break;
    case 1: s = s1; d = d1; n = n1; break;
    case 2: s = s2; d = d2; n = n2; break;
    default: s = s3; d = d3; n = n3; break;
  }
  const int i = (blockIdx.x * 256 + threadIdx.x) * 4;
  if (i < n) {
    const float4 v = *reinterpret_cast<const float4*>(s + i);
    u16x4 o;
    o[0] = f2bf(v.x); o[1] = f2bf(v.y); o[2] = f2bf(v.z); o[3] = f2bf(v.w);
    *reinterpret_cast<u16x4*>(d + i) = o;
  }
}

// ---------------- LayerNorm: fp32 in, bf16 out -----------------------------
__global__ __launch_bounds__(256) void ln_kernel(
    const float* __restrict__ x, const float* __restrict__ w,
    ushort_t* __restrict__ y) {
  const int row = blockIdx.x;
  const float4 v = reinterpret_cast<const float4*>(x + (size_t)row * D_)[threadIdx.x];
  float s  = v.x + v.y + v.z + v.w;
  float ss = v.x * v.x + v.y * v.y + v.z * v.z + v.w * v.w;
  __shared__ float red[8];
  const int wave = threadIdx.x >> 6, lane = threadIdx.x & 63;
  const float ws1 = wave_reduce_sum(s);
  const float ws2 = wave_reduce_sum(ss);
  if (lane == 0) { red[wave] = ws1; red[4 + wave] = ws2; }
  __syncthreads();
  const float tot  = red[0] + red[1] + red[2] + red[3];
  const float tot2 = red[4] + red[5] + red[6] + red[7];
  const float mu  = tot * (1.0f / D_);
  const float var = tot2 * (1.0f / D_) - mu * mu;
  const float inv = rsqrtf(var + 1e-5f);
  const float4 wv = reinterpret_cast<const float4*>(w)[threadIdx.x];
  u16x4 o;
  o[0] = f2bf((v.x - mu) * inv * wv.x);
  o[1] = f2bf((v.y - mu) * inv * wv.y);
  o[2] = f2bf((v.z - mu) * inv * wv.z);
  o[3] = f2bf((v.w - mu) * inv * wv.w);
  reinterpret_cast<u16x4*>(y + (size_t)row * D_)[threadIdx.x] = o;
}

// gelu(u) = u * sigmoid(2c(u+0.044715u^3)); exp2 domain, k=2c*log2e.
__device__ __forceinline__ float gelu_tanh(float u) {
  const float p = u + 0.044715f * u * u * u;
  const float e = exp2_fast(-2.3022078f * p);
  return u * rcp_fast(1.0f + e);
}

// ---------------- bf16 MFMA GEMM 128x128, BK=32, 3-stage counted-vmcnt -----
// C[M,N] = A[M,K] * W[N,K]^T. FUSE bits: 1=+bias, 2=gelu, 4=+res (fp32).
// QKV=1: n<1024 -> rope+scale -> Qo (B,H,S,Dh); 1024..2048 -> rope -> Ko;
//        n>=2048 -> transposed Vt (B,H,Dh,S).
template <int FUSE, int OUTBF, int QKV>
__global__ __launch_bounds__(256) void gemm_bt(
    const ushort_t* __restrict__ A, const ushort_t* __restrict__ W,
    const float* __restrict__ bias, const float* __restrict__ res,
    void* __restrict__ Cv, ushort_t* __restrict__ VtOut,
    const float* __restrict__ cosb, const float* __restrict__ sinb,
    ushort_t* __restrict__ Qo, ushort_t* __restrict__ Ko,
    int M, int N, int K, int sm, int sn, int rects_n) {
  __shared__ ushort_t As[3][128 * 32];   // 8 KB / stage
  __shared__ ushort_t Bs[3][128 * 32];   // 8 KB / stage  -> 48 KB total
  const int tid = threadIdx.x;
  const int wave = tid >> 6, lane = tid & 63;
  const int l15 = lane & 15, quad = lane >> 4;

  // XCD-rectangle swizzle
  const int lin = blockIdx.x;
  const int xcd = lin & 7, j = lin >> 3;
  const int rm = xcd / rects_n, rn = xcd % rects_n;
  const int m0 = (rm * sm + (j % sm)) * 128;
  const int n0 = (rn * sn + (j / sm)) * 128;
  const int wm = (wave & 1) * 64, wn = (wave >> 1) * 64;

  const int srow = tid >> 2;                               // 0..63
  const int gcol = (((tid & 3) ^ ((srow >> 1) & 3)) * 8);  // swizzled src col
  const ushort_t* Ag = A + (size_t)(m0 + srow) * K + gcol;
  const ushort_t* Wg = W + (size_t)(n0 + srow) * K + gcol;

  f32x4 acc[4][4] = {};
  const int rslot = (quad ^ ((l15 >> 1) & 3)) * 8;         // read-side swizzle

  const int NI = K >> 5;
  async_copy16(Ag,               &As[0][tid * 8]);
  async_copy16(Ag + 64 * K,      &As[0][2048 + tid * 8]);
  async_copy16(Wg,               &Bs[0][tid * 8]);
  async_copy16(Wg + 64 * K,      &Bs[0][2048 + tid * 8]);
  if (NI > 1) {
    async_copy16(Ag + 32,          &As[1][tid * 8]);
    async_copy16(Ag + 64 * K + 32, &As[1][2048 + tid * 8]);
    async_copy16(Wg + 32,          &Bs[1][tid * 8]);
    async_copy16(Wg + 64 * K + 32, &Bs[1][2048 + tid * 8]);
  }

  int st = 0;
  for (int i = 0; i < NI; ++i) {
    if (i + 1 < NI) asm volatile("s_waitcnt vmcnt(4)" ::: "memory");
    else            asm volatile("s_waitcnt vmcnt(0)" ::: "memory");
    __builtin_amdgcn_s_barrier();
    __builtin_amdgcn_sched_barrier(0);   // pin: no LDS reads above barrier
    if (i + 2 < NI) {
      const int k2 = (i + 2) << 5;
      const int nb = (st >= 1) ? st - 1 : st + 2;   // (st+2)%3
      async_copy16(Ag + k2,          &As[nb][tid * 8]);
      async_copy16(Ag + 64 * K + k2, &As[nb][2048 + tid * 8]);
      async_copy16(Wg + k2,          &Bs[nb][tid * 8]);
      async_copy16(Wg + 64 * K + k2, &Bs[nb][2048 + tid * 8]);
    }
    bf16x8 af[4], bfr[4];
    #pragma unroll
    for (int ii = 0; ii < 4; ++ii) {
      af[ii]  = *(const bf16x8*)&As[st][(wm + ii * 16 + l15) * 32 + rslot];
      bfr[ii] = *(const bf16x8*)&Bs[st][(wn + ii * 16 + l15) * 32 + rslot];
    }
    #pragma unroll
    for (int ii = 0; ii < 4; ++ii)
      #pragma unroll
      for (int jj = 0; jj < 4; ++jj)
        acc[ii][jj] = __builtin_amdgcn_mfma_f32_16x16x32_bf16(af[ii], bfr[jj], acc[ii][jj], 0, 0, 0);
    st = (st == 2) ? 0 : st + 1;
  }

  const int nsec = QKV ? ((n0 + wn) >> 10) : 0;   // wave-uniform: 0=q,1=k,2=v

  #pragma unroll
  for (int i = 0; i < 4; ++i) {
    const int mb = m0 + wm + i * 16 + quad * 4;     // + r
    if (QKV && nsec != 2) {
      // ---- fused RoPE epilogue (q or k), all in-register -----------------
      const int hh = ((n0 + wn) >> 6) & 15;
      const int bb = mb >> 11;
      const int s0r = mb & (S_ - 1);
      ushort_t* dst = (nsec == 0) ? Qo : Ko;
      const float qs = (nsec == 0) ? 0.18033688736f : 1.0f;  // 0.125*log2e
      #pragma unroll
      for (int r = 0; r < 4; ++r) {
        const int s = s0r + r;
        const float c0 = cosb[s * 64 + l15];
        const float c1 = cosb[s * 64 + 16 + l15];
        const float sn0 = sinb[s * 64 + l15];
        const float sn1 = sinb[s * 64 + 16 + l15];
        const float v0 = acc[i][0][r], v1 = acc[i][1][r];
        const float v2 = acc[i][2][r], v3 = acc[i][3][r];
        const size_t base = (((size_t)(bb * H_ + hh) * S_ + s)) * DH_ + l15;
        dst[base]      = f2bf((v0 * c0 - v2 * sn0) * qs);   // d = l15
        dst[base + 16] = f2bf((v1 * c1 - v3 * sn1) * qs);   // d = 16+l15
        dst[base + 32] = f2bf((v2 * c0 + v0 * sn0) * qs);   // d = 32+l15
        dst[base + 48] = f2bf((v3 * c1 + v1 * sn1) * qs);   // d = 48+l15
      }
      continue;
    }
    #pragma unroll
    for (int jj = 0; jj < 4; ++jj) {
      const int n = n0 + wn + jj * 16 + l15;
      float cv[4];
      #pragma unroll
      for (int r = 0; r < 4; ++r) {
        float c = acc[i][jj][r];
        if (FUSE & 1) c += bias[n];
        if (FUSE & 2) c = gelu_tanh(c);
        if (FUSE & 4) c += res[(size_t)(mb + r) * N + n];
        cv[r] = c;
      }
      if (QKV && nsec == 2) {
        const int d  = n & 63;
        const int hh = (n >> 6) & 15;
        const int bb = mb >> 11;
        const int ss = mb & (S_ - 1);
        u16x4 pk;
        #pragma unroll
        for (int r = 0; r < 4; ++r) pk[r] = f2bf(cv[r]);
        *(u16x4*)&VtOut[((size_t)(bb * H_ + hh) * DH_ + d) * S_ + ss] = pk;
      } else {
        #pragma unroll
        for (int r = 0; r < 4; ++r) {
          if (OUTBF) ((ushort_t*)Cv)[(size_t)(mb + r) * N + n] = f2bf(cv[r]);
          else       ((float*)Cv)[(size_t)(mb + r) * N + n]   = cv[r];
        }
      }
    }
  }
}

// ---------------- bf16 MFMA GEMM 64x128, BK=64, 8 waves ---------------------
// A operand DIRECT global->VGPR (double-buffered ping/pong); only B staged
// in LDS (3-stage ring, 2 loads/thread/stage -> counted vmcnt below).
// Issue order per iter (pinned by sched_barrier): [wait][barrier]
// [loadA it+1][stageB it+2][B ds_read + MFMA]. Steady-state outstanding at
// iter top = stage_j(2,oldest) + A_j(4) + stage_{j+1}(2) -> vmcnt(6).
template <int FUSE, int OUTBF>
__global__ __launch_bounds__(512, 4) void gemm64_bt(
    const ushort_t* __restrict__ A, const ushort_t* __restrict__ W,
    const float* __restrict__ bias, const float* __restrict__ res,
    void* __restrict__ Cv, int M, int N, int K, int sm, int sn, int rects_n) {
  __shared__ ushort_t Bs[3][128 * 64];   // 16 KB / stage -> 48 KB total
  const int tid = threadIdx.x;           // 0..511
  const int wave = tid >> 6, lane = tid & 63;
  const int l15 = lane & 15, quad = lane >> 4;

  const int lin = blockIdx.x;
  const int xcd = lin & 7, j = lin >> 3;
  const int rm = xcd / rects_n, rn = xcd % rects_n;
  const int m0 = (rm * sm + (j % sm)) * 64;
  const int n0 = (rn * sn + (j / sm)) * 128;
  const int wm = (wave & 1) * 32;        // 2 M-groups of 32
  const int wn = (wave >> 1) * 32;       // 4 N-groups of 32

  // B staging: 512 threads x 16 B x 2 shots, swizzled source col.
  const int srow = tid >> 3;                        // 0..63
  const int scol = (((tid & 7) ^ (srow & 7)) * 8);
  const ushort_t* Wg = W + (size_t)(n0 + srow) * K + scol;

  // A direct: per-lane row base (row = m0+wm+l15 / +16, col chunk quad*8).
  const ushort_t* Aw = A + (size_t)(m0 + wm + l15) * K + quad * 8;

  f32x4 acc[2][2] = {};
  const int NI = K >> 6;

  bf16x8 aP[2][2], aQ[2][2];             // ping/pong A fragments [i][kk]

  auto loadA = [&](bf16x8 (&dst)[2][2], int it) {
    const int k0 = it << 6;
    #pragma unroll
    for (int i = 0; i < 2; ++i)
      #pragma unroll
      for (int kk = 0; kk < 2; ++kk)
        dst[i][kk] = *(const bf16x8*)(Aw + (size_t)(i * 16) * K + k0 + kk * 32);
  };
  auto stageB = [&](int buf, int it) {
    const int k0 = it << 6;
    async_copy16(Wg + k0,          &Bs[buf][tid * 8]);
    async_copy16(Wg + 64 * K + k0, &Bs[buf][4096 + tid * 8]);
  };

  // prologue (issue order pinned): A0 (4) | stage0 (2) | stage1 (2)
  loadA(aP, 0);
  __builtin_amdgcn_sched_barrier(0);
  stageB(0, 0);
  __builtin_amdgcn_sched_barrier(0);
  stageB(1, 1);

  auto body = [&](bf16x8 (&cur)[2][2], bf16x8 (&nxt)[2][2], int it, int st) {
    // drain stage it (oldest); keep A_it + stage it+1 in flight
    if (it == 0)          asm volatile("s_waitcnt vmcnt(2)" ::: "memory");
    else if (it + 1 < NI) asm volatile("s_waitcnt vmcnt(6)" ::: "memory");
    else                  asm volatile("s_waitcnt vmcnt(4)" ::: "memory");
    __builtin_amdgcn_s_barrier();
    __builtin_amdgcn_sched_barrier(0);
    if (it + 1 < NI) loadA(nxt, it + 1);
    __builtin_amdgcn_sched_barrier(0);   // pin A-loads BEFORE staging issues
    if (it + 2 < NI) {
      const int nb = (st >= 1) ? st - 1 : st + 2;   // (st+2)%3
      stageB(nb, it + 2);
    }
    #pragma unroll
    for (int kk = 0; kk < 2; ++kk) {
      const int slot = (((kk * 4 + quad) ^ (l15 & 7)) * 8);
      bf16x8 bfr[2];
      #pragma unroll
      for (int jj = 0; jj < 2; ++jj)
        bfr[jj] = *(const bf16x8*)&Bs[st][(wn + jj * 16 + l15) * 64 + slot];
      #pragma unroll
      for (int i = 0; i < 2; ++i)
        #pragma unroll
        for (int jj = 0; jj < 2; ++jj)
          acc[i][jj] = __builtin_amdgcn_mfma_f32_16x16x32_bf16(cur[i][kk], bfr[jj], acc[i][jj], 0, 0, 0);
    }
  };

  int st = 0;
  for (int it = 0; it < NI; it += 2) {   // NI is 16 or 64 (even)
    body(aP, aQ, it, st);     st = (st == 2) ? 0 : st + 1;
    body(aQ, aP, it + 1, st); st = (st == 2) ? 0 : st + 1;
  }

  #pragma unroll
  for (int i = 0; i < 2; ++i) {
    const int mb = m0 + wm + i * 16 + quad * 4;     // + r
    #pragma unroll
    for (int jj = 0; jj < 2; ++jj) {
      const int n = n0 + wn + jj * 16 + l15;
      #pragma unroll
      for (int r = 0; r < 4; ++r) {
        float c = acc[i][jj][r];
        if (FUSE & 1) c += bias[n];
        if (FUSE & 2) c = gelu_tanh(c);
        if (FUSE & 4) c += res[(size_t)(mb + r) * N + n];
        if (OUTBF) ((ushort_t*)Cv)[(size_t)(mb + r) * N + n] = f2bf(c);
        else       ((float*)Cv)[(size_t)(mb + r) * N + n]   = c;
      }
    }
  }
}

// ---------------- Block-cooperative LDS-staged flash attention -------------
// 1 block = 8 waves x 16 Q rows = 128 adjacent rows of one (b,h), 512 thr.
#define PPAD 72

__global__ __launch_bounds__(512) void attn_kernel(
    const ushort_t* __restrict__ Qb, const ushort_t* __restrict__ Kb,
    const ushort_t* __restrict__ Vt, ushort_t* __restrict__ O) {
  __shared__ ushort_t Ks[2][64 * 64];   // 8 KB / stage
  __shared__ ushort_t Vs[2][64 * 64];   // 8 KB / stage -> 32 KB
  __shared__ ushort_t Plds[8][16 * PPAD];  // 18 KB -> 51.2 KB total

  const int tid  = threadIdx.x;
  const int wave = tid >> 6;           // 0..7
  const int lane = tid & 63;
  const int l15 = lane & 15, quad = lane >> 4;

  const int lin = blockIdx.x;
  const int bh  = lin & 31;
  const int u   = lin >> 5;            // 0..15
  const int g   = (u < 8) ? (15 - u) : (u - 8);   // pair sums to 15
  const int b = bh >> 4, h = bh & 15;
  const int q0 = g * 128 + wave * 16;  // this wave's 16 rows

  const int nch_w   = (q0 >> 6) + 1;   // chunks this wave needs
  const int nch_max = 2 * g + 2;       // chunks staged by the block

  const ushort_t* Kbh = Kb + (size_t)bh * S_ * DH_;
  const ushort_t* Vbh = Vt + (size_t)bh * DH_ * S_;

  // 512 threads x 16 B = one full 64x64 tile each for K and V.
  auto stage = [&](int buf, int c) {
    const int k0s = c << 6;
    const int row  = tid >> 3;                 // 0..63
    const int slot = tid & 7;
    const int scol = ((slot ^ (row & 7)) * 8);
    async_copy16(Kbh + (size_t)(k0s + row) * DH_ + scol, &Ks[buf][tid * 8]);
    async_copy16(Vbh + (size_t)row * S_ + k0s + scol,    &Vs[buf][tid * 8]);
  };

  bf16x8 qb[2];
  {
    const ushort_t* qptr = Qb + ((size_t)bh * S_ + q0 + l15) * DH_ + quad * 8;
    qb[0] = *(const bf16x8*)(qptr);
    qb[1] = *(const bf16x8*)(qptr + 32);
  }

  f32x4 o_acc[4] = {};
  float m_run = -1e30f, l_run = 0.0f;

  stage(0, 0);                          // prologue

  for (int c = 0; c < nch_max; ++c) {
    const int st = c & 1;
    __syncthreads();                    // drains stage issued last iter
    if (c + 1 < nch_max) stage(st ^ 1, c + 1);
    if (c >= nch_w) continue;           // idle wave (tail chunk)
    const int k0 = c << 6;

    bf16x8 ka[4][2];
    #pragma unroll
    for (int kt = 0; kt < 4; ++kt) {
      const int row = kt * 16 + l15;
      const int bse = row * 64, rx = row & 7;
      ka[kt][0] = *(const bf16x8*)&Ks[st][bse + ((quad ^ rx) * 8)];
      ka[kt][1] = *(const bf16x8*)&Ks[st][bse + (((4 + quad) ^ rx) * 8)];
    }

    f32x4 s_t[4];
    __builtin_amdgcn_s_setprio(1);
    #pragma unroll
    for (int kt = 0; kt < 4; ++kt) {
      f32x4 z = {0.0f, 0.0f, 0.0f, 0.0f};
      z = __builtin_amdgcn_mfma_f32_16x16x32_bf16(ka[kt][0], qb[0], z, 0, 0, 0);
      z = __builtin_amdgcn_mfma_f32_16x16x32_bf16(ka[kt][1], qb[1], z, 0, 0, 0);
      s_t[kt] = z;
    }
    __builtin_amdgcn_s_setprio(0);

    if (c == nch_w - 1) {               // diagonal chunk: causal mask
      const int query = q0 + l15;
      #pragma unroll
      for (int kt = 0; kt < 4; ++kt)
        #pragma unroll
        for (int r = 0; r < 4; ++r)
          if (k0 + kt * 16 + quad * 4 + r > query) s_t[kt][r] = -1e30f;
    }

    {
      float mx = -1e30f;
      #pragma unroll
      for (int kt = 0; kt < 4; ++kt)
        #pragma unroll
        for (int r = 0; r < 4; ++r) mx = fmaxf(mx, s_t[kt][r]);
      mx = fmaxf(mx, __shfl_xor(mx, 16, 64));
      mx = fmaxf(mx, __shfl_xor(mx, 32, 64));
      // T13 defer-max: skip rescale while max grows < 8 (P bounded by 2^8).
      if (!__all(mx <= m_run + 8.0f)) {
        const float m_new = fmaxf(m_run, mx);
        const float alpha = exp2_fast(m_run - m_new);
        l_run *= alpha;
        #pragma unroll
        for (int mt = 0; mt < 4; ++mt)
          #pragma unroll
          for (int r = 0; r < 4; ++r) o_acc[mt][r] *= alpha;
        m_run = m_new;
      }
      float rs = 0.0f;
      #pragma unroll
      for (int kt = 0; kt < 4; ++kt)
        #pragma unroll
        for (int r = 0; r < 4; ++r) {
          const float e = exp2_fast(s_t[kt][r] - m_run);
          s_t[kt][r] = e;
          rs += e;
        }
      rs += __shfl_xor(rs, 16, 64);
      rs += __shfl_xor(rs, 32, 64);
      l_run += rs;
    }

    bf16x8 va[4][2];
    #pragma unroll
    for (int mt = 0; mt < 4; ++mt) {
      const int row = mt * 16 + l15;    // dh
      const int bse = row * 64, rx = row & 7;
      va[mt][0] = *(const bf16x8*)&Vs[st][bse + ((quad ^ rx) * 8)];
      va[mt][1] = *(const bf16x8*)&Vs[st][bse + (((4 + quad) ^ rx) * 8)];
    }

    {
      ushort_t* Pw = &Plds[wave][0];
      #pragma unroll
      for (int kt = 0; kt < 4; ++kt) {
        u32x2 wpair;
        wpair[0] = (unsigned)f2bf(s_t[kt][0]) | ((unsigned)f2bf(s_t[kt][1]) << 16);
        wpair[1] = (unsigned)f2bf(s_t[kt][2]) | ((unsigned)f2bf(s_t[kt][3]) << 16);
        *(u32x2*)&Pw[l15 * PPAD + kt * 16 + quad * 4] = wpair;
      }
      asm volatile("s_waitcnt lgkmcnt(0)" ::: "memory");
      const bf16x8 pb0 = *(const bf16x8*)&Pw[l15 * PPAD + quad * 8];
      const bf16x8 pb1 = *(const bf16x8*)&Pw[l15 * PPAD + 32 + quad * 8];
      __builtin_amdgcn_s_setprio(1);
      #pragma unroll
      for (int mt = 0; mt < 4; ++mt) {
        o_acc[mt] = __builtin_amdgcn_mfma_f32_16x16x32_bf16(va[mt][0], pb0, o_acc[mt], 0, 0, 0);
        o_acc[mt] = __builtin_amdgcn_mfma_f32_16x16x32_bf16(va[mt][1], pb1, o_acc[mt], 0, 0, 0);
      }
      __builtin_amdgcn_s_setprio(0);
    }
  }

  {
    const float inv = 1.0f / l_run;
    #pragma unroll
    for (int mt = 0; mt < 4; ++mt) {
      u16x4 pk;
      #pragma unroll
      for (int r = 0; r < 4; ++r) pk[r] = f2bf(o_acc[mt][r] * inv);
      *(u16x4*)&O[(((size_t)b * S_ + q0 + l15) * H_ + h) * DH_ + mt * 16 + quad * 4] = pk;
    }
  }
}

// ---------------------------------------------------------------------------
extern "C" void kernel_launch(void* const* d_in, const int* in_sizes, int n_in,
                              void* d_out, int out_size, void* d_ws, size_t ws_size,
                              hipStream_t stream) {
  const float* x       = (const float*)d_in[0];
  const float* rot_cos = (const float*)d_in[1];
  const float* rot_sin = (const float*)d_in[2];
  const float* ln1_w   = (const float*)d_in[3];
  const float* w_qkv   = (const float*)d_in[4];
  const float* w_out   = (const float*)d_in[5];
  const float* ln2_w   = (const float*)d_in[6];
  const float* w_mlp1  = (const float*)d_in[7];
  const float* b_mlp1  = (const float*)d_in[8];
  const float* w_mlp2  = (const float*)d_in[9];
  const float* b_mlp2  = (const float*)d_in[10];
  float* out = (float*)d_out;

  char* wsb = (char*)d_ws;
  const size_t MB = 1u << 20;
  ushort_t* h1_bf  = (ushort_t*)(wsb + 0 * MB);    // 8 MB  (reused as h2)
  ushort_t* q_bf   = (ushort_t*)(wsb + 32 * MB);   // 8 MB
  ushort_t* k_bf   = (ushort_t*)(wsb + 40 * MB);   // 8 MB
  ushort_t* v_t    = (ushort_t*)(wsb + 48 * MB);   // 8 MB (B,H,Dh,S)
  ushort_t* o_bf   = (ushort_t*)(wsb + 56 * MB);   // 8 MB
  float*    x2     = (float*)   (wsb + 64 * MB);   // 16 MB
  ushort_t* u_bf   = (ushort_t*)(wsb + 80 * MB);   // 32 MB
  ushort_t* wq_bf  = (ushort_t*)(wsb + 112 * MB);  // 6 MB
  ushort_t* wo_bf  = (ushort_t*)(wsb + 118 * MB);  // 2 MB
  ushort_t* w1_bf  = (ushort_t*)(wsb + 120 * MB);  // 8 MB
  ushort_t* w2_bf  = (ushort_t*)(wsb + 128 * MB);  // 8 MB -> 136 MB total
  (void)ws_size; (void)in_sizes; (void)n_in; (void)out_size;

  dim3 b256(256);

  // 0) weights -> bf16
  cast_w_kernel<<<dim3(4096, 4), b256, 0, stream>>>(
      w_qkv, wq_bf, 3 * D_ * D_, w_out, wo_bf, D_ * D_,
      w_mlp1, w1_bf, MLP_ * D_, w_mlp2, w2_bf, MLP_ * D_);
  // 1) h1 = LN(x) * ln1_w -> bf16
  ln_kernel<<<dim3(ROWS_), b256, 0, stream>>>(x, ln1_w, h1_bf);
  // 2) qkv = h1 @ w_qkv^T with FUSED rope: q -> q_bf (scaled), k -> k_bf,
  //    V -> v_t (B,H,Dh,S).
  gemm_bt<0, 1, 1><<<dim3(768), b256, 0, stream>>>(
      h1_bf, wq_bf, nullptr, nullptr, nullptr, v_t,
      rot_cos, rot_sin, q_bf, k_bf, ROWS_, 3 * D_, D_, 16, 6, 4);
  // 3) block-cooperative flash attention (8 waves x 16 rows) -> o bf16
  attn_kernel<<<dim3(512), dim3(512), 0, stream>>>(q_bf, k_bf, v_t, o_bf);
  // 4) x2 = x + o @ w_out^T -> fp32
  gemm64_bt<4, 0><<<dim3(512), dim3(512), 0, stream>>>(
      o_bf, wo_bf, nullptr, x, x2, ROWS_, D_, D_, 16, 4, 2);
  // 5) h2 = LN(x2) * ln2_w -> bf16
  ln_kernel<<<dim3(ROWS_), b256, 0, stream>>>(x2, ln2_w, h1_bf);
  // 6) u = gelu(h2 @ w_mlp1^T + b1) -> bf16
  gemm_bt<3, 1, 0><<<dim3(1024), b256, 0, stream>>>(
      h1_bf, w1_bf, b_mlp1, nullptr, u_bf, nullptr,
      nullptr, nullptr, nullptr, nullptr, ROWS_, MLP_, D_, 16, 8, 4);
  // 7) out = x2 + u @ w_mlp2^T + b2 -> fp32
  gemm64_bt<5, 0><<<dim3(512), dim3(512), 0, stream>>>(
      u_bf, w2_bf, b_mlp2, x2, out, ROWS_, D_, MLP_, 16, 4, 2);
}

// Round 11
// 331.184 us; speedup vs baseline: 1.3307x; 1.3307x over previous
//
#include <hip/hip_runtime.h>
#include <hip/hip_bf16.h>
#include <math.h>

// ---------------------------------------------------------------------------
// DDiTBlockCausal: B=2, S=2048, D=1024, H=16, Dh=64, MLP=4096, fp32 I/O.
// Round 18 (recovery): revert gemm64_bt to the R16 8-wave LDS version.
// R17's A-direct-to-VGPR regressed 58.6 -> 148.7 us: with 8 waves x 32x32,
// waves {0,2,4,6} share the same 32 A-rows, so per-wave registers load each
// A element 4x (LDS staging existed to de-duplicate) -- FETCH +23 MB, L2
// thrash, poor 16-row-strided coalescing. LESSON: only wave-private
// operands (attn's Q) may skip LDS; wave-shared operands must stage.
// Everything here is byte-identical to R16 (measured 330.8 us).
// ---------------------------------------------------------------------------

#define B_ 2
#define S_ 2048
#define D_ 1024
#define H_ 16
#define DH_ 64
#define MLP_ 4096
#define ROWS_ (B_ * S_)   // 4096

typedef short bf16x8 __attribute__((ext_vector_type(8)));
typedef float f32x4 __attribute__((ext_vector_type(4)));
typedef unsigned short ushort_t;
typedef ushort_t u16x4 __attribute__((ext_vector_type(4)));
typedef unsigned int u32x2 __attribute__((ext_vector_type(2)));

__device__ __forceinline__ float wave_reduce_sum(float v) {
  #pragma unroll
  for (int off = 32; off > 0; off >>= 1) v += __shfl_down(v, off, 64);
  return v;
}

__device__ __forceinline__ ushort_t f2bf(float v) {
  __hip_bfloat16 h = __float2bfloat16(v);
  return *(ushort_t*)&h;
}
__device__ __forceinline__ float bf2f(ushort_t u) {
  unsigned int v = ((unsigned int)u) << 16;
  union { unsigned int i; float f; } c; c.i = v; return c.f;
}

__device__ __forceinline__ float exp2_fast(float x) {
#if __has_builtin(__builtin_amdgcn_exp2f)
  return __builtin_amdgcn_exp2f(x);
#else
  return exp2f(x);
#endif
}
__device__ __forceinline__ float rcp_fast(float x) {
#if __has_builtin(__builtin_amdgcn_rcpf)
  return __builtin_amdgcn_rcpf(x);
#else
  return 1.0f / x;
#endif
}

__device__ __forceinline__ void async_copy16(const void* g, void* l) {
  __builtin_amdgcn_global_load_lds(
      (const __attribute__((address_space(1))) void*)g,
      (__attribute__((address_space(3))) void*)l, 16, 0, 0);
}

// ---------------- weight cast fp32 -> bf16 (4 tensors, blockIdx.y picks) ---
__global__ __launch_bounds__(256) void cast_w_kernel(
    const float* __restrict__ s0, ushort_t* __restrict__ d0, int n0,
    const float* __restrict__ s1, ushort_t* __restrict__ d1, int n1,
    const float* __restrict__ s2, ushort_t* __restrict__ d2, int n2,
    const float* __restrict__ s3, ushort_t* __restrict__ d3, int n3) {
  const float* s; ushort_t* d; int n;
  switch (blockIdx.y) {
    case 0: s = s0; d = d0; n = n0; break;
    case 1: s = s1; d = d1; n = n1; break;
    case 2: s = s2; d = d2; n = n2; break;
    default: s = s3; d = d3; n = n3; break;
  }
  const int i = (blockIdx.x * 256 + threadIdx.x) * 4;
  if (i < n) {
    const float4 v = *reinterpret_cast<const float4*>(s + i);
    u16x4 o;
    o[0] = f2bf(v.x); o[1] = f2bf(v.y); o[2] = f2bf(v.z); o[3] = f2bf(v.w);
    *reinterpret_cast<u16x4*>(d + i) = o;
  }
}

// ---------------- LayerNorm: fp32 in, bf16 out -----------------------------
__global__ __launch_bounds__(256) void ln_kernel(
    const float* __restrict__ x, const float* __restrict__ w,
    ushort_t* __restrict__ y) {
  const int row = blockIdx.x;
  const float4 v = reinterpret_cast<const float4*>(x + (size_t)row * D_)[threadIdx.x];
  float s  = v.x + v.y + v.z + v.w;
  float ss = v.x * v.x + v.y * v.y + v.z * v.z + v.w * v.w;
  __shared__ float red[8];
  const int wave = threadIdx.x >> 6, lane = threadIdx.x & 63;
  const float ws1 = wave_reduce_sum(s);
  const float ws2 = wave_reduce_sum(ss);
  if (lane == 0) { red[wave] = ws1; red[4 + wave] = ws2; }
  __syncthreads();
  const float tot  = red[0] + red[1] + red[2] + red[3];
  const float tot2 = red[4] + red[5] + red[6] + red[7];
  const float mu  = tot * (1.0f / D_);
  const float var = tot2 * (1.0f / D_) - mu * mu;
  const float inv = rsqrtf(var + 1e-5f);
  const float4 wv = reinterpret_cast<const float4*>(w)[threadIdx.x];
  u16x4 o;
  o[0] = f2bf((v.x - mu) * inv * wv.x);
  o[1] = f2bf((v.y - mu) * inv * wv.y);
  o[2] = f2bf((v.z - mu) * inv * wv.z);
  o[3] = f2bf((v.w - mu) * inv * wv.w);
  reinterpret_cast<u16x4*>(y + (size_t)row * D_)[threadIdx.x] = o;
}

// gelu(u) = u * sigmoid(2c(u+0.044715u^3)); exp2 domain, k=2c*log2e.
__device__ __forceinline__ float gelu_tanh(float u) {
  const float p = u + 0.044715f * u * u * u;
  const float e = exp2_fast(-2.3022078f * p);
  return u * rcp_fast(1.0f + e);
}

// ---------------- bf16 MFMA GEMM 128x128, BK=32, 3-stage counted-vmcnt -----
// C[M,N] = A[M,K] * W[N,K]^T. FUSE bits: 1=+bias, 2=gelu, 4=+res (fp32).
// QKV=1: n<1024 -> rope+scale -> Qo (B,H,S,Dh); 1024..2048 -> rope -> Ko;
//        n>=2048 -> transposed Vt (B,H,Dh,S).
template <int FUSE, int OUTBF, int QKV>
__global__ __launch_bounds__(256) void gemm_bt(
    const ushort_t* __restrict__ A, const ushort_t* __restrict__ W,
    const float* __restrict__ bias, const float* __restrict__ res,
    void* __restrict__ Cv, ushort_t* __restrict__ VtOut,
    const float* __restrict__ cosb, const float* __restrict__ sinb,
    ushort_t* __restrict__ Qo, ushort_t* __restrict__ Ko,
    int M, int N, int K, int sm, int sn, int rects_n) {
  __shared__ ushort_t As[3][128 * 32];   // 8 KB / stage
  __shared__ ushort_t Bs[3][128 * 32];   // 8 KB / stage  -> 48 KB total
  const int tid = threadIdx.x;
  const int wave = tid >> 6, lane = tid & 63;
  const int l15 = lane & 15, quad = lane >> 4;

  // XCD-rectangle swizzle
  const int lin = blockIdx.x;
  const int xcd = lin & 7, j = lin >> 3;
  const int rm = xcd / rects_n, rn = xcd % rects_n;
  const int m0 = (rm * sm + (j % sm)) * 128;
  const int n0 = (rn * sn + (j / sm)) * 128;
  const int wm = (wave & 1) * 64, wn = (wave >> 1) * 64;

  const int srow = tid >> 2;                               // 0..63
  const int gcol = (((tid & 3) ^ ((srow >> 1) & 3)) * 8);  // swizzled src col
  const ushort_t* Ag = A + (size_t)(m0 + srow) * K + gcol;
  const ushort_t* Wg = W + (size_t)(n0 + srow) * K + gcol;

  f32x4 acc[4][4] = {};
  const int rslot = (quad ^ ((l15 >> 1) & 3)) * 8;         // read-side swizzle

  const int NI = K >> 5;
  async_copy16(Ag,               &As[0][tid * 8]);
  async_copy16(Ag + 64 * K,      &As[0][2048 + tid * 8]);
  async_copy16(Wg,               &Bs[0][tid * 8]);
  async_copy16(Wg + 64 * K,      &Bs[0][2048 + tid * 8]);
  if (NI > 1) {
    async_copy16(Ag + 32,          &As[1][tid * 8]);
    async_copy16(Ag + 64 * K + 32, &As[1][2048 + tid * 8]);
    async_copy16(Wg + 32,          &Bs[1][tid * 8]);
    async_copy16(Wg + 64 * K + 32, &Bs[1][2048 + tid * 8]);
  }

  int st = 0;
  for (int i = 0; i < NI; ++i) {
    if (i + 1 < NI) asm volatile("s_waitcnt vmcnt(4)" ::: "memory");
    else            asm volatile("s_waitcnt vmcnt(0)" ::: "memory");
    __builtin_amdgcn_s_barrier();
    __builtin_amdgcn_sched_barrier(0);   // pin: no LDS reads above barrier
    if (i + 2 < NI) {
      const int k2 = (i + 2) << 5;
      const int nb = (st >= 1) ? st - 1 : st + 2;   // (st+2)%3
      async_copy16(Ag + k2,          &As[nb][tid * 8]);
      async_copy16(Ag + 64 * K + k2, &As[nb][2048 + tid * 8]);
      async_copy16(Wg + k2,          &Bs[nb][tid * 8]);
      async_copy16(Wg + 64 * K + k2, &Bs[nb][2048 + tid * 8]);
    }
    bf16x8 af[4], bfr[4];
    #pragma unroll
    for (int ii = 0; ii < 4; ++ii) {
      af[ii]  = *(const bf16x8*)&As[st][(wm + ii * 16 + l15) * 32 + rslot];
      bfr[ii] = *(const bf16x8*)&Bs[st][(wn + ii * 16 + l15) * 32 + rslot];
    }
    #pragma unroll
    for (int ii = 0; ii < 4; ++ii)
      #pragma unroll
      for (int jj = 0; jj < 4; ++jj)
        acc[ii][jj] = __builtin_amdgcn_mfma_f32_16x16x32_bf16(af[ii], bfr[jj], acc[ii][jj], 0, 0, 0);
    st = (st == 2) ? 0 : st + 1;
  }

  const int nsec = QKV ? ((n0 + wn) >> 10) : 0;   // wave-uniform: 0=q,1=k,2=v

  #pragma unroll
  for (int i = 0; i < 4; ++i) {
    const int mb = m0 + wm + i * 16 + quad * 4;     // + r
    if (QKV && nsec != 2) {
      // ---- fused RoPE epilogue (q or k), all in-register -----------------
      const int hh = ((n0 + wn) >> 6) & 15;
      const int bb = mb >> 11;
      const int s0r = mb & (S_ - 1);
      ushort_t* dst = (nsec == 0) ? Qo : Ko;
      const float qs = (nsec == 0) ? 0.18033688736f : 1.0f;  // 0.125*log2e
      #pragma unroll
      for (int r = 0; r < 4; ++r) {
        const int s = s0r + r;
        const float c0 = cosb[s * 64 + l15];
        const float c1 = cosb[s * 64 + 16 + l15];
        const float sn0 = sinb[s * 64 + l15];
        const float sn1 = sinb[s * 64 + 16 + l15];
        const float v0 = acc[i][0][r], v1 = acc[i][1][r];
        const float v2 = acc[i][2][r], v3 = acc[i][3][r];
        const size_t base = (((size_t)(bb * H_ + hh) * S_ + s)) * DH_ + l15;
        dst[base]      = f2bf((v0 * c0 - v2 * sn0) * qs);   // d = l15
        dst[base + 16] = f2bf((v1 * c1 - v3 * sn1) * qs);   // d = 16+l15
        dst[base + 32] = f2bf((v2 * c0 + v0 * sn0) * qs);   // d = 32+l15
        dst[base + 48] = f2bf((v3 * c1 + v1 * sn1) * qs);   // d = 48+l15
      }
      continue;
    }
    #pragma unroll
    for (int jj = 0; jj < 4; ++jj) {
      const int n = n0 + wn + jj * 16 + l15;
      float cv[4];
      #pragma unroll
      for (int r = 0; r < 4; ++r) {
        float c = acc[i][jj][r];
        if (FUSE & 1) c += bias[n];
        if (FUSE & 2) c = gelu_tanh(c);
        if (FUSE & 4) c += res[(size_t)(mb + r) * N + n];
        cv[r] = c;
      }
      if (QKV && nsec == 2) {
        const int d  = n & 63;
        const int hh = (n >> 6) & 15;
        const int bb = mb >> 11;
        const int ss = mb & (S_ - 1);
        u16x4 pk;
        #pragma unroll
        for (int r = 0; r < 4; ++r) pk[r] = f2bf(cv[r]);
        *(u16x4*)&VtOut[((size_t)(bb * H_ + hh) * DH_ + d) * S_ + ss] = pk;
      } else {
        #pragma unroll
        for (int r = 0; r < 4; ++r) {
          if (OUTBF) ((ushort_t*)Cv)[(size_t)(mb + r) * N + n] = f2bf(cv[r]);
          else       ((float*)Cv)[(size_t)(mb + r) * N + n]   = cv[r];
        }
      }
    }
  }
}

// ---------------- bf16 MFMA GEMM 64x128, BK=64, 8 waves, 3-stage ring ------
// For N=1024 GEMMs (outproj, mlp2). 512 threads; each wave owns a 32x32
// sub-tile (2M x 4N). 3 loads/stage/thread -> counted vmcnt(3).
template <int FUSE, int OUTBF>
__global__ __launch_bounds__(512) void gemm64_bt(
    const ushort_t* __restrict__ A, const ushort_t* __restrict__ W,
    const float* __restrict__ bias, const float* __restrict__ res,
    void* __restrict__ Cv, int M, int N, int K, int sm, int sn, int rects_n) {
  __shared__ ushort_t As[3][64 * 64];    // 8 KB / stage
  __shared__ ushort_t Bs[3][128 * 64];   // 16 KB / stage -> 72 KB total
  const int tid = threadIdx.x;           // 0..511
  const int wave = tid >> 6, lane = tid & 63;
  const int l15 = lane & 15, quad = lane >> 4;

  const int lin = blockIdx.x;
  const int xcd = lin & 7, j = lin >> 3;
  const int rm = xcd / rects_n, rn = xcd % rects_n;
  const int m0 = (rm * sm + (j % sm)) * 64;
  const int n0 = (rn * sn + (j / sm)) * 128;
  const int wm = (wave & 1) * 32;        // 2 M-groups of 32
  const int wn = (wave >> 1) * 32;       // 4 N-groups of 32

  // Staging: 512 threads x 16 B: A tile (64x64) in 1 shot, B (128x64) in 2.
  const int srow = tid >> 3;                        // 0..63
  const int scol = (((tid & 7) ^ (srow & 7)) * 8);  // swizzled source col
  const ushort_t* Ag = A + (size_t)(m0 + srow) * K + scol;
  const ushort_t* Wg = W + (size_t)(n0 + srow) * K + scol;

  f32x4 acc[2][2] = {};

  const int NI = K >> 6;
  // prologue: stages 0 and 1 (3 loads/thread each)
  async_copy16(Ag,           &As[0][tid * 8]);
  async_copy16(Wg,           &Bs[0][tid * 8]);
  async_copy16(Wg + 64 * K,  &Bs[0][4096 + tid * 8]);
  if (NI > 1) {
    async_copy16(Ag + 64,          &As[1][tid * 8]);
    async_copy16(Wg + 64,          &Bs[1][tid * 8]);
    async_copy16(Wg + 64 * K + 64, &Bs[1][4096 + tid * 8]);
  }

  int st = 0;
  for (int it = 0; it < NI; ++it) {
    if (it + 1 < NI) asm volatile("s_waitcnt vmcnt(3)" ::: "memory");
    else             asm volatile("s_waitcnt vmcnt(0)" ::: "memory");
    __builtin_amdgcn_s_barrier();
    __builtin_amdgcn_sched_barrier(0);
    if (it + 2 < NI) {
      const int k2 = (it + 2) << 6;
      const int nb = (st >= 1) ? st - 1 : st + 2;   // (st+2)%3
      async_copy16(Ag + k2,          &As[nb][tid * 8]);
      async_copy16(Wg + k2,          &Bs[nb][tid * 8]);
      async_copy16(Wg + 64 * K + k2, &Bs[nb][4096 + tid * 8]);
    }
    #pragma unroll
    for (int kk = 0; kk < 2; ++kk) {
      const int slot = (((kk * 4 + quad) ^ (l15 & 7)) * 8);
      bf16x8 af[2], bfr[2];
      #pragma unroll
      for (int i = 0; i < 2; ++i)
        af[i] = *(const bf16x8*)&As[st][(wm + i * 16 + l15) * 64 + slot];
      #pragma unroll
      for (int jj = 0; jj < 2; ++jj)
        bfr[jj] = *(const bf16x8*)&Bs[st][(wn + jj * 16 + l15) * 64 + slot];
      #pragma unroll
      for (int i = 0; i < 2; ++i)
        #pragma unroll
        for (int jj = 0; jj < 2; ++jj)
          acc[i][jj] = __builtin_amdgcn_mfma_f32_16x16x32_bf16(af[i], bfr[jj], acc[i][jj], 0, 0, 0);
    }
    st = (st == 2) ? 0 : st + 1;
  }

  #pragma unroll
  for (int i = 0; i < 2; ++i) {
    const int mb = m0 + wm + i * 16 + quad * 4;     // + r
    #pragma unroll
    for (int jj = 0; jj < 2; ++jj) {
      const int n = n0 + wn + jj * 16 + l15;
      #pragma unroll
      for (int r = 0; r < 4; ++r) {
        float c = acc[i][jj][r];
        if (FUSE & 1) c += bias[n];
        if (FUSE & 2) c = gelu_tanh(c);
        if (FUSE & 4) c += res[(size_t)(mb + r) * N + n];
        if (OUTBF) ((ushort_t*)Cv)[(size_t)(mb + r) * N + n] = f2bf(c);
        else       ((float*)Cv)[(size_t)(mb + r) * N + n]   = c;
      }
    }
  }
}

// ---------------- Block-cooperative LDS-staged flash attention -------------
// 1 block = 8 waves x 16 Q rows = 128 adjacent rows of one (b,h), 512 thr.
#define PPAD 72

__global__ __launch_bounds__(512) void attn_kernel(
    const ushort_t* __restrict__ Qb, const ushort_t* __restrict__ Kb,
    const ushort_t* __restrict__ Vt, ushort_t* __restrict__ O) {
  __shared__ ushort_t Ks[2][64 * 64];   // 8 KB / stage
  __shared__ ushort_t Vs[2][64 * 64];   // 8 KB / stage -> 32 KB
  __shared__ ushort_t Plds[8][16 * PPAD];  // 18 KB -> 51.2 KB total

  const int tid  = threadIdx.x;
  const int wave = tid >> 6;           // 0..7
  const int lane = tid & 63;
  const int l15 = lane & 15, quad = lane >> 4;

  const int lin = blockIdx.x;
  const int bh  = lin & 31;
  const int u   = lin >> 5;            // 0..15
  const int g   = (u < 8) ? (15 - u) : (u - 8);   // pair sums to 15
  const int b = bh >> 4, h = bh & 15;
  const int q0 = g * 128 + wave * 16;  // this wave's 16 rows

  const int nch_w   = (q0 >> 6) + 1;   // chunks this wave needs
  const int nch_max = 2 * g + 2;       // chunks staged by the block

  const ushort_t* Kbh = Kb + (size_t)bh * S_ * DH_;
  const ushort_t* Vbh = Vt + (size_t)bh * DH_ * S_;

  // 512 threads x 16 B = one full 64x64 tile each for K and V.
  auto stage = [&](int buf, int c) {
    const int k0s = c << 6;
    const int row  = tid >> 3;                 // 0..63
    const int slot = tid & 7;
    const int scol = ((slot ^ (row & 7)) * 8);
    async_copy16(Kbh + (size_t)(k0s + row) * DH_ + scol, &Ks[buf][tid * 8]);
    async_copy16(Vbh + (size_t)row * S_ + k0s + scol,    &Vs[buf][tid * 8]);
  };

  bf16x8 qb[2];
  {
    const ushort_t* qptr = Qb + ((size_t)bh * S_ + q0 + l15) * DH_ + quad * 8;
    qb[0] = *(const bf16x8*)(qptr);
    qb[1] = *(const bf16x8*)(qptr + 32);
  }

  f32x4 o_acc[4] = {};
  float m_run = -1e30f, l_run = 0.0f;

  stage(0, 0);                          // prologue

  for (int c = 0; c < nch_max; ++c) {
    const int st = c & 1;
    __syncthreads();                    // drains stage issued last iter
    if (c + 1 < nch_max) stage(st ^ 1, c + 1);
    if (c >= nch_w) continue;           // idle wave (tail chunk)
    const int k0 = c << 6;

    bf16x8 ka[4][2];
    #pragma unroll
    for (int kt = 0; kt < 4; ++kt) {
      const int row = kt * 16 + l15;
      const int bse = row * 64, rx = row & 7;
      ka[kt][0] = *(const bf16x8*)&Ks[st][bse + ((quad ^ rx) * 8)];
      ka[kt][1] = *(const bf16x8*)&Ks[st][bse + (((4 + quad) ^ rx) * 8)];
    }

    f32x4 s_t[4];
    __builtin_amdgcn_s_setprio(1);
    #pragma unroll
    for (int kt = 0; kt < 4; ++kt) {
      f32x4 z = {0.0f, 0.0f, 0.0f, 0.0f};
      z = __builtin_amdgcn_mfma_f32_16x16x32_bf16(ka[kt][0], qb[0], z, 0, 0, 0);
      z = __builtin_amdgcn_mfma_f32_16x16x32_bf16(ka[kt][1], qb[1], z, 0, 0, 0);
      s_t[kt] = z;
    }
    __builtin_amdgcn_s_setprio(0);

    if (c == nch_w - 1) {               // diagonal chunk: causal mask
      const int query = q0 + l15;
      #pragma unroll
      for (int kt = 0; kt < 4; ++kt)
        #pragma unroll
        for (int r = 0; r < 4; ++r)
          if (k0 + kt * 16 + quad * 4 + r > query) s_t[kt][r] = -1e30f;
    }

    {
      float mx = -1e30f;
      #pragma unroll
      for (int kt = 0; kt < 4; ++kt)
        #pragma unroll
        for (int r = 0; r < 4; ++r) mx = fmaxf(mx, s_t[kt][r]);
      mx = fmaxf(mx, __shfl_xor(mx, 16, 64));
      mx = fmaxf(mx, __shfl_xor(mx, 32, 64));
      // T13 defer-max: skip rescale while max grows < 8 (P bounded by 2^8).
      if (!__all(mx <= m_run + 8.0f)) {
        const float m_new = fmaxf(m_run, mx);
        const float alpha = exp2_fast(m_run - m_new);
        l_run *= alpha;
        #pragma unroll
        for (int mt = 0; mt < 4; ++mt)
          #pragma unroll
          for (int r = 0; r < 4; ++r) o_acc[mt][r] *= alpha;
        m_run = m_new;
      }
      float rs = 0.0f;
      #pragma unroll
      for (int kt = 0; kt < 4; ++kt)
        #pragma unroll
        for (int r = 0; r < 4; ++r) {
          const float e = exp2_fast(s_t[kt][r] - m_run);
          s_t[kt][r] = e;
          rs += e;
        }
      rs += __shfl_xor(rs, 16, 64);
      rs += __shfl_xor(rs, 32, 64);
      l_run += rs;
    }

    bf16x8 va[4][2];
    #pragma unroll
    for (int mt = 0; mt < 4; ++mt) {
      const int row = mt * 16 + l15;    // dh
      const int bse = row * 64, rx = row & 7;
      va[mt][0] = *(const bf16x8*)&Vs[st][bse + ((quad ^ rx) * 8)];
      va[mt][1] = *(const bf16x8*)&Vs[st][bse + (((4 + quad) ^ rx) * 8)];
    }

    {
      ushort_t* Pw = &Plds[wave][0];
      #pragma unroll
      for (int kt = 0; kt < 4; ++kt) {
        u32x2 wpair;
        wpair[0] = (unsigned)f2bf(s_t[kt][0]) | ((unsigned)f2bf(s_t[kt][1]) << 16);
        wpair[1] = (unsigned)f2bf(s_t[kt][2]) | ((unsigned)f2bf(s_t[kt][3]) << 16);
        *(u32x2*)&Pw[l15 * PPAD + kt * 16 + quad * 4] = wpair;
      }
      asm volatile("s_waitcnt lgkmcnt(0)" ::: "memory");
      const bf16x8 pb0 = *(const bf16x8*)&Pw[l15 * PPAD + quad * 8];
      const bf16x8 pb1 = *(const bf16x8*)&Pw[l15 * PPAD + 32 + quad * 8];
      __builtin_amdgcn_s_setprio(1);
      #pragma unroll
      for (int mt = 0; mt < 4; ++mt) {
        o_acc[mt] = __builtin_amdgcn_mfma_f32_16x16x32_bf16(va[mt][0], pb0, o_acc[mt], 0, 0, 0);
        o_acc[mt] = __builtin_amdgcn_mfma_f32_16x16x32_bf16(va[mt][1], pb1, o_acc[mt], 0, 0, 0);
      }
      __builtin_amdgcn_s_setprio(0);
    }
  }

  {
    const float inv = 1.0f / l_run;
    #pragma unroll
    for (int mt = 0; mt < 4; ++mt) {
      u16x4 pk;
      #pragma unroll
      for (int r = 0; r < 4; ++r) pk[r] = f2bf(o_acc[mt][r] * inv);
      *(u16x4*)&O[(((size_t)b * S_ + q0 + l15) * H_ + h) * DH_ + mt * 16 + quad * 4] = pk;
    }
  }
}

// ---------------------------------------------------------------------------
extern "C" void kernel_launch(void* const* d_in, const int* in_sizes, int n_in,
                              void* d_out, int out_size, void* d_ws, size_t ws_size,
                              hipStream_t stream) {
  const float* x       = (const float*)d_in[0];
  const float* rot_cos = (const float*)d_in[1];
  const float* rot_sin = (const float*)d_in[2];
  const float* ln1_w   = (const float*)d_in[3];
  const float* w_qkv   = (const float*)d_in[4];
  const float* w_out   = (const float*)d_in[5];
  const float* ln2_w   = (const float*)d_in[6];
  const float* w_mlp1  = (const float*)d_in[7];
  const float* b_mlp1  = (const float*)d_in[8];
  const float* w_mlp2  = (const float*)d_in[9];
  const float* b_mlp2  = (const float*)d_in[10];
  float* out = (float*)d_out;

  char* wsb = (char*)d_ws;
  const size_t MB = 1u << 20;
  ushort_t* h1_bf  = (ushort_t*)(wsb + 0 * MB);    // 8 MB  (reused as h2)
  ushort_t* q_bf   = (ushort_t*)(wsb + 32 * MB);   // 8 MB
  ushort_t* k_bf   = (ushort_t*)(wsb + 40 * MB);   // 8 MB
  ushort_t* v_t    = (ushort_t*)(wsb + 48 * MB);   // 8 MB (B,H,Dh,S)
  ushort_t* o_bf   = (ushort_t*)(wsb + 56 * MB);   // 8 MB
  float*    x2     = (float*)   (wsb + 64 * MB);   // 16 MB
  ushort_t* u_bf   = (ushort_t*)(wsb + 80 * MB);   // 32 MB
  ushort_t* wq_bf  = (ushort_t*)(wsb + 112 * MB);  // 6 MB
  ushort_t* wo_bf  = (ushort_t*)(wsb + 118 * MB);  // 2 MB
  ushort_t* w1_bf  = (ushort_t*)(wsb + 120 * MB);  // 8 MB
  ushort_t* w2_bf  = (ushort_t*)(wsb + 128 * MB);  // 8 MB -> 136 MB total
  (void)ws_size; (void)in_sizes; (void)n_in; (void)out_size;

  dim3 b256(256);

  // 0) weights -> bf16
  cast_w_kernel<<<dim3(4096, 4), b256, 0, stream>>>(
      w_qkv, wq_bf, 3 * D_ * D_, w_out, wo_bf, D_ * D_,
      w_mlp1, w1_bf, MLP_ * D_, w_mlp2, w2_bf, MLP_ * D_);
  // 1) h1 = LN(x) * ln1_w -> bf16
  ln_kernel<<<dim3(ROWS_), b256, 0, stream>>>(x, ln1_w, h1_bf);
  // 2) qkv = h1 @ w_qkv^T with FUSED rope: q -> q_bf (scaled), k -> k_bf,
  //    V -> v_t (B,H,Dh,S).
  gemm_bt<0, 1, 1><<<dim3(768), b256, 0, stream>>>(
      h1_bf, wq_bf, nullptr, nullptr, nullptr, v_t,
      rot_cos, rot_sin, q_bf, k_bf, ROWS_, 3 * D_, D_, 16, 6, 4);
  // 3) block-cooperative flash attention (8 waves x 16 rows) -> o bf16
  attn_kernel<<<dim3(512), dim3(512), 0, stream>>>(q_bf, k_bf, v_t, o_bf);
  // 4) x2 = x + o @ w_out^T -> fp32
  gemm64_bt<4, 0><<<dim3(512), dim3(512), 0, stream>>>(
      o_bf, wo_bf, nullptr, x, x2, ROWS_, D_, D_, 16, 4, 2);
  // 5) h2 = LN(x2) * ln2_w -> bf16
  ln_kernel<<<dim3(ROWS_), b256, 0, stream>>>(x2, ln2_w, h1_bf);
  // 6) u = gelu(h2 @ w_mlp1^T + b1) -> bf16
  gemm_bt<3, 1, 0><<<dim3(1024), b256, 0, stream>>>(
      h1_bf, w1_bf, b_mlp1, nullptr, u_bf, nullptr,
      nullptr, nullptr, nullptr, nullptr, ROWS_, MLP_, D_, 16, 8, 4);
  // 7) out = x2 + u @ w_mlp2^T + b2 -> fp32
  gemm64_bt<5, 0><<<dim3(512), dim3(512), 0, stream>>>(
      u_bf, w2_bf, b_mlp2, x2, out, ROWS_, D_, MLP_, 16, 4, 2);
}

// Round 12
// 327.468 us; speedup vs baseline: 1.3459x; 1.0113x over previous
//
#include <hip/hip_runtime.h>
#include <hip/hip_bf16.h>
#include <math.h>

// ---------------------------------------------------------------------------
// DDiTBlockCausal: B=2, S=2048, D=1024, H=16, Dh=64, MLP=4096, fp32 I/O.
// Round 19:
//  - gemm_bt QKV V-epilogue: the transposed v_t store was 8 B per 64 B line
//    (16 lanes -> 16 d-rows 4 KB apart): WRITE_SIZE 64 MB vs 24 ideal (R18
//    counters). Now V-blocks bounce their 128x128 tile through LDS
//    (u16x4 ds_write_b64 packed along rows, stride 136 shorts = 2-way-free
//    banks, 16B-aligned) and store v_t COALESCED along S (full lines).
//    Staging LDS re-carved as one smem[] array and reused (barrier first).
//  - everything else byte-identical to R18 (verified 331.2 us).
// ---------------------------------------------------------------------------

#define B_ 2
#define S_ 2048
#define D_ 1024
#define H_ 16
#define DH_ 64
#define MLP_ 4096
#define ROWS_ (B_ * S_)   // 4096

typedef short bf16x8 __attribute__((ext_vector_type(8)));
typedef float f32x4 __attribute__((ext_vector_type(4)));
typedef unsigned short ushort_t;
typedef ushort_t u16x4 __attribute__((ext_vector_type(4)));
typedef unsigned int u32x2 __attribute__((ext_vector_type(2)));

__device__ __forceinline__ float wave_reduce_sum(float v) {
  #pragma unroll
  for (int off = 32; off > 0; off >>= 1) v += __shfl_down(v, off, 64);
  return v;
}

__device__ __forceinline__ ushort_t f2bf(float v) {
  __hip_bfloat16 h = __float2bfloat16(v);
  return *(ushort_t*)&h;
}
__device__ __forceinline__ float bf2f(ushort_t u) {
  unsigned int v = ((unsigned int)u) << 16;
  union { unsigned int i; float f; } c; c.i = v; return c.f;
}

__device__ __forceinline__ float exp2_fast(float x) {
#if __has_builtin(__builtin_amdgcn_exp2f)
  return __builtin_amdgcn_exp2f(x);
#else
  return exp2f(x);
#endif
}
__device__ __forceinline__ float rcp_fast(float x) {
#if __has_builtin(__builtin_amdgcn_rcpf)
  return __builtin_amdgcn_rcpf(x);
#else
  return 1.0f / x;
#endif
}

__device__ __forceinline__ void async_copy16(const void* g, void* l) {
  __builtin_amdgcn_global_load_lds(
      (const __attribute__((address_space(1))) void*)g,
      (__attribute__((address_space(3))) void*)l, 16, 0, 0);
}

// ---------------- weight cast fp32 -> bf16 (4 tensors, blockIdx.y picks) ---
__global__ __launch_bounds__(256) void cast_w_kernel(
    const float* __restrict__ s0, ushort_t* __restrict__ d0, int n0,
    const float* __restrict__ s1, ushort_t* __restrict__ d1, int n1,
    const float* __restrict__ s2, ushort_t* __restrict__ d2, int n2,
    const float* __restrict__ s3, ushort_t* __restrict__ d3, int n3) {
  const float* s; ushort_t* d; int n;
  switch (blockIdx.y) {
    case 0: s = s0; d = d0; n = n0; break;
    case 1: s = s1; d = d1; n = n1; break;
    case 2: s = s2; d = d2; n = n2; break;
    default: s = s3; d = d3; n = n3; break;
  }
  const int i = (blockIdx.x * 256 + threadIdx.x) * 4;
  if (i < n) {
    const float4 v = *reinterpret_cast<const float4*>(s + i);
    u16x4 o;
    o[0] = f2bf(v.x); o[1] = f2bf(v.y); o[2] = f2bf(v.z); o[3] = f2bf(v.w);
    *reinterpret_cast<u16x4*>(d + i) = o;
  }
}

// ---------------- LayerNorm: fp32 in, bf16 out -----------------------------
__global__ __launch_bounds__(256) void ln_kernel(
    const float* __restrict__ x, const float* __restrict__ w,
    ushort_t* __restrict__ y) {
  const int row = blockIdx.x;
  const float4 v = reinterpret_cast<const float4*>(x + (size_t)row * D_)[threadIdx.x];
  float s  = v.x + v.y + v.z + v.w;
  float ss = v.x * v.x + v.y * v.y + v.z * v.z + v.w * v.w;
  __shared__ float red[8];
  const int wave = threadIdx.x >> 6, lane = threadIdx.x & 63;
  const float ws1 = wave_reduce_sum(s);
  const float ws2 = wave_reduce_sum(ss);
  if (lane == 0) { red[wave] = ws1; red[4 + wave] = ws2; }
  __syncthreads();
  const float tot  = red[0] + red[1] + red[2] + red[3];
  const float tot2 = red[4] + red[5] + red[6] + red[7];
  const float mu  = tot * (1.0f / D_);
  const float var = tot2 * (1.0f / D_) - mu * mu;
  const float inv = rsqrtf(var + 1e-5f);
  const float4 wv = reinterpret_cast<const float4*>(w)[threadIdx.x];
  u16x4 o;
  o[0] = f2bf((v.x - mu) * inv * wv.x);
  o[1] = f2bf((v.y - mu) * inv * wv.y);
  o[2] = f2bf((v.z - mu) * inv * wv.z);
  o[3] = f2bf((v.w - mu) * inv * wv.w);
  reinterpret_cast<u16x4*>(y + (size_t)row * D_)[threadIdx.x] = o;
}

// gelu(u) = u * sigmoid(2c(u+0.044715u^3)); exp2 domain, k=2c*log2e.
__device__ __forceinline__ float gelu_tanh(float u) {
  const float p = u + 0.044715f * u * u * u;
  const float e = exp2_fast(-2.3022078f * p);
  return u * rcp_fast(1.0f + e);
}

// ---------------- bf16 MFMA GEMM 128x128, BK=32, 3-stage counted-vmcnt -----
// C[M,N] = A[M,K] * W[N,K]^T. FUSE bits: 1=+bias, 2=gelu, 4=+res (fp32).
// QKV=1: n<1024 -> rope+scale -> Qo (B,H,S,Dh); 1024..2048 -> rope -> Ko;
//        n>=2048 -> LDS-transposed coalesced store to Vt (B,H,Dh,S).
template <int FUSE, int OUTBF, int QKV>
__global__ __launch_bounds__(256) void gemm_bt(
    const ushort_t* __restrict__ A, const ushort_t* __restrict__ W,
    const float* __restrict__ bias, const float* __restrict__ res,
    void* __restrict__ Cv, ushort_t* __restrict__ VtOut,
    const float* __restrict__ cosb, const float* __restrict__ sinb,
    ushort_t* __restrict__ Qo, ushort_t* __restrict__ Ko,
    int M, int N, int K, int sm, int sn, int rects_n) {
  __shared__ ushort_t smem[24576];        // 48 KB: As 3 stages | Bs 3 stages
  ushort_t* Asm = smem;                   // stage p at p*4096 shorts
  ushort_t* Bsm = smem + 12288;
  const int tid = threadIdx.x;
  const int wave = tid >> 6, lane = tid & 63;
  const int l15 = lane & 15, quad = lane >> 4;

  // XCD-rectangle swizzle
  const int lin = blockIdx.x;
  const int xcd = lin & 7, j = lin >> 3;
  const int rm = xcd / rects_n, rn = xcd % rects_n;
  const int m0 = (rm * sm + (j % sm)) * 128;
  const int n0 = (rn * sn + (j / sm)) * 128;
  const int wm = (wave & 1) * 64, wn = (wave >> 1) * 64;

  const int srow = tid >> 2;                               // 0..63
  const int gcol = (((tid & 3) ^ ((srow >> 1) & 3)) * 8);  // swizzled src col
  const ushort_t* Ag = A + (size_t)(m0 + srow) * K + gcol;
  const ushort_t* Wg = W + (size_t)(n0 + srow) * K + gcol;

  f32x4 acc[4][4] = {};
  const int rslot = (quad ^ ((l15 >> 1) & 3)) * 8;         // read-side swizzle

  const int NI = K >> 5;
  async_copy16(Ag,               &Asm[tid * 8]);
  async_copy16(Ag + 64 * K,      &Asm[2048 + tid * 8]);
  async_copy16(Wg,               &Bsm[tid * 8]);
  async_copy16(Wg + 64 * K,      &Bsm[2048 + tid * 8]);
  if (NI > 1) {
    async_copy16(Ag + 32,          &Asm[4096 + tid * 8]);
    async_copy16(Ag + 64 * K + 32, &Asm[4096 + 2048 + tid * 8]);
    async_copy16(Wg + 32,          &Bsm[4096 + tid * 8]);
    async_copy16(Wg + 64 * K + 32, &Bsm[4096 + 2048 + tid * 8]);
  }

  int st = 0;
  for (int i = 0; i < NI; ++i) {
    if (i + 1 < NI) asm volatile("s_waitcnt vmcnt(4)" ::: "memory");
    else            asm volatile("s_waitcnt vmcnt(0)" ::: "memory");
    __builtin_amdgcn_s_barrier();
    __builtin_amdgcn_sched_barrier(0);   // pin: no LDS reads above barrier
    if (i + 2 < NI) {
      const int k2 = (i + 2) << 5;
      const int nb = (st >= 1) ? st - 1 : st + 2;   // (st+2)%3
      async_copy16(Ag + k2,          &Asm[nb * 4096 + tid * 8]);
      async_copy16(Ag + 64 * K + k2, &Asm[nb * 4096 + 2048 + tid * 8]);
      async_copy16(Wg + k2,          &Bsm[nb * 4096 + tid * 8]);
      async_copy16(Wg + 64 * K + k2, &Bsm[nb * 4096 + 2048 + tid * 8]);
    }
    bf16x8 af[4], bfr[4];
    #pragma unroll
    for (int ii = 0; ii < 4; ++ii) {
      af[ii]  = *(const bf16x8*)&Asm[st * 4096 + (wm + ii * 16 + l15) * 32 + rslot];
      bfr[ii] = *(const bf16x8*)&Bsm[st * 4096 + (wn + ii * 16 + l15) * 32 + rslot];
    }
    #pragma unroll
    for (int ii = 0; ii < 4; ++ii)
      #pragma unroll
      for (int jj = 0; jj < 4; ++jj)
        acc[ii][jj] = __builtin_amdgcn_mfma_f32_16x16x32_bf16(af[ii], bfr[jj], acc[ii][jj], 0, 0, 0);
    st = (st == 2) ? 0 : st + 1;
  }

  if (QKV && (n0 >> 10) == 2) {
    // ---- V block: LDS-transpose then coalesced Vt stores -----------------
    // Ct[col][row]: 128 cols x 136-short stride (272 B: 16B-aligned rows,
    // write stride == 4 banks -> 2-way (free) on b64 writes).
    ushort_t* Ct = smem;                  // 34 KB <= 48 KB
    __syncthreads();                      // all waves done with stage LDS
    #pragma unroll
    for (int i = 0; i < 4; ++i) {
      const int rowb = wm + i * 16 + quad * 4;
      #pragma unroll
      for (int jj = 0; jj < 4; ++jj) {
        const int col = wn + jj * 16 + l15;
        u16x4 pk;
        #pragma unroll
        for (int r = 0; r < 4; ++r) pk[r] = f2bf(acc[i][jj][r]);
        *(u16x4*)&Ct[col * 136 + rowb] = pk;
      }
    }
    __syncthreads();
    // read out: 256 thr, col = tid>>1 (0..127), s-half = (tid&1)*64.
    const int col = tid >> 1;
    const int sh  = (tid & 1) * 64;
    const int bb  = m0 >> 11;
    const int s0  = m0 & (S_ - 1);
    const int hh  = ((n0 >> 6) & 15) + (col >> 6);
    const int d   = col & 63;
    ushort_t* dst = &VtOut[((size_t)(bb * H_ + hh) * DH_ + d) * S_ + s0 + sh];
    const ushort_t* src = &Ct[col * 136 + sh];
    #pragma unroll
    for (int q8 = 0; q8 < 8; ++q8)
      *(bf16x8*)(dst + q8 * 8) = *(const bf16x8*)(src + q8 * 8);
    return;
  }

  const int nsec = QKV ? ((n0 + wn) >> 10) : 0;   // wave-uniform: 0=q,1=k

  #pragma unroll
  for (int i = 0; i < 4; ++i) {
    const int mb = m0 + wm + i * 16 + quad * 4;     // + r
    if (QKV) {
      // ---- fused RoPE epilogue (q or k), all in-register -----------------
      const int hh = ((n0 + wn) >> 6) & 15;
      const int bb = mb >> 11;
      const int s0r = mb & (S_ - 1);
      ushort_t* dst = (nsec == 0) ? Qo : Ko;
      const float qs = (nsec == 0) ? 0.18033688736f : 1.0f;  // 0.125*log2e
      #pragma unroll
      for (int r = 0; r < 4; ++r) {
        const int s = s0r + r;
        const float c0 = cosb[s * 64 + l15];
        const float c1 = cosb[s * 64 + 16 + l15];
        const float sn0 = sinb[s * 64 + l15];
        const float sn1 = sinb[s * 64 + 16 + l15];
        const float v0 = acc[i][0][r], v1 = acc[i][1][r];
        const float v2 = acc[i][2][r], v3 = acc[i][3][r];
        const size_t base = (((size_t)(bb * H_ + hh) * S_ + s)) * DH_ + l15;
        dst[base]      = f2bf((v0 * c0 - v2 * sn0) * qs);   // d = l15
        dst[base + 16] = f2bf((v1 * c1 - v3 * sn1) * qs);   // d = 16+l15
        dst[base + 32] = f2bf((v2 * c0 + v0 * sn0) * qs);   // d = 32+l15
        dst[base + 48] = f2bf((v3 * c1 + v1 * sn1) * qs);   // d = 48+l15
      }
      continue;
    }
    #pragma unroll
    for (int jj = 0; jj < 4; ++jj) {
      const int n = n0 + wn + jj * 16 + l15;
      float cv[4];
      #pragma unroll
      for (int r = 0; r < 4; ++r) {
        float c = acc[i][jj][r];
        if (FUSE & 1) c += bias[n];
        if (FUSE & 2) c = gelu_tanh(c);
        if (FUSE & 4) c += res[(size_t)(mb + r) * N + n];
        cv[r] = c;
      }
      #pragma unroll
      for (int r = 0; r < 4; ++r) {
        if (OUTBF) ((ushort_t*)Cv)[(size_t)(mb + r) * N + n] = f2bf(cv[r]);
        else       ((float*)Cv)[(size_t)(mb + r) * N + n]   = cv[r];
      }
    }
  }
}

// ---------------- bf16 MFMA GEMM 64x128, BK=64, 8 waves, 3-stage ring ------
// For N=1024 GEMMs (outproj, mlp2). 512 threads; each wave owns a 32x32
// sub-tile (2M x 4N). 3 loads/stage/thread -> counted vmcnt(3).
template <int FUSE, int OUTBF>
__global__ __launch_bounds__(512) void gemm64_bt(
    const ushort_t* __restrict__ A, const ushort_t* __restrict__ W,
    const float* __restrict__ bias, const float* __restrict__ res,
    void* __restrict__ Cv, int M, int N, int K, int sm, int sn, int rects_n) {
  __shared__ ushort_t As[3][64 * 64];    // 8 KB / stage
  __shared__ ushort_t Bs[3][128 * 64];   // 16 KB / stage -> 72 KB total
  const int tid = threadIdx.x;           // 0..511
  const int wave = tid >> 6, lane = tid & 63;
  const int l15 = lane & 15, quad = lane >> 4;

  const int lin = blockIdx.x;
  const int xcd = lin & 7, j = lin >> 3;
  const int rm = xcd / rects_n, rn = xcd % rects_n;
  const int m0 = (rm * sm + (j % sm)) * 64;
  const int n0 = (rn * sn + (j / sm)) * 128;
  const int wm = (wave & 1) * 32;        // 2 M-groups of 32
  const int wn = (wave >> 1) * 32;       // 4 N-groups of 32

  const int srow = tid >> 3;                        // 0..63
  const int scol = (((tid & 7) ^ (srow & 7)) * 8);  // swizzled source col
  const ushort_t* Ag = A + (size_t)(m0 + srow) * K + scol;
  const ushort_t* Wg = W + (size_t)(n0 + srow) * K + scol;

  f32x4 acc[2][2] = {};

  const int NI = K >> 6;
  async_copy16(Ag,           &As[0][tid * 8]);
  async_copy16(Wg,           &Bs[0][tid * 8]);
  async_copy16(Wg + 64 * K,  &Bs[0][4096 + tid * 8]);
  if (NI > 1) {
    async_copy16(Ag + 64,          &As[1][tid * 8]);
    async_copy16(Wg + 64,          &Bs[1][tid * 8]);
    async_copy16(Wg + 64 * K + 64, &Bs[1][4096 + tid * 8]);
  }

  int st = 0;
  for (int it = 0; it < NI; ++it) {
    if (it + 1 < NI) asm volatile("s_waitcnt vmcnt(3)" ::: "memory");
    else             asm volatile("s_waitcnt vmcnt(0)" ::: "memory");
    __builtin_amdgcn_s_barrier();
    __builtin_amdgcn_sched_barrier(0);
    if (it + 2 < NI) {
      const int k2 = (it + 2) << 6;
      const int nb = (st >= 1) ? st - 1 : st + 2;   // (st+2)%3
      async_copy16(Ag + k2,          &As[nb][tid * 8]);
      async_copy16(Wg + k2,          &Bs[nb][tid * 8]);
      async_copy16(Wg + 64 * K + k2, &Bs[nb][4096 + tid * 8]);
    }
    #pragma unroll
    for (int kk = 0; kk < 2; ++kk) {
      const int slot = (((kk * 4 + quad) ^ (l15 & 7)) * 8);
      bf16x8 af[2], bfr[2];
      #pragma unroll
      for (int i = 0; i < 2; ++i)
        af[i] = *(const bf16x8*)&As[st][(wm + i * 16 + l15) * 64 + slot];
      #pragma unroll
      for (int jj = 0; jj < 2; ++jj)
        bfr[jj] = *(const bf16x8*)&Bs[st][(wn + jj * 16 + l15) * 64 + slot];
      #pragma unroll
      for (int i = 0; i < 2; ++i)
        #pragma unroll
        for (int jj = 0; jj < 2; ++jj)
          acc[i][jj] = __builtin_amdgcn_mfma_f32_16x16x32_bf16(af[i], bfr[jj], acc[i][jj], 0, 0, 0);
    }
    st = (st == 2) ? 0 : st + 1;
  }

  #pragma unroll
  for (int i = 0; i < 2; ++i) {
    const int mb = m0 + wm + i * 16 + quad * 4;     // + r
    #pragma unroll
    for (int jj = 0; jj < 2; ++jj) {
      const int n = n0 + wn + jj * 16 + l15;
      #pragma unroll
      for (int r = 0; r < 4; ++r) {
        float c = acc[i][jj][r];
        if (FUSE & 1) c += bias[n];
        if (FUSE & 2) c = gelu_tanh(c);
        if (FUSE & 4) c += res[(size_t)(mb + r) * N + n];
        if (OUTBF) ((ushort_t*)Cv)[(size_t)(mb + r) * N + n] = f2bf(c);
        else       ((float*)Cv)[(size_t)(mb + r) * N + n]   = c;
      }
    }
  }
}

// ---------------- Block-cooperative LDS-staged flash attention -------------
// 1 block = 8 waves x 16 Q rows = 128 adjacent rows of one (b,h), 512 thr.
#define PPAD 72

__global__ __launch_bounds__(512) void attn_kernel(
    const ushort_t* __restrict__ Qb, const ushort_t* __restrict__ Kb,
    const ushort_t* __restrict__ Vt, ushort_t* __restrict__ O) {
  __shared__ ushort_t Ks[2][64 * 64];   // 8 KB / stage
  __shared__ ushort_t Vs[2][64 * 64];   // 8 KB / stage -> 32 KB
  __shared__ ushort_t Plds[8][16 * PPAD];  // 18 KB -> 51.2 KB total

  const int tid  = threadIdx.x;
  const int wave = tid >> 6;           // 0..7
  const int lane = tid & 63;
  const int l15 = lane & 15, quad = lane >> 4;

  const int lin = blockIdx.x;
  const int bh  = lin & 31;
  const int u   = lin >> 5;            // 0..15
  const int g   = (u < 8) ? (15 - u) : (u - 8);   // pair sums to 15
  const int b = bh >> 4, h = bh & 15;
  const int q0 = g * 128 + wave * 16;  // this wave's 16 rows

  const int nch_w   = (q0 >> 6) + 1;   // chunks this wave needs
  const int nch_max = 2 * g + 2;       // chunks staged by the block

  const ushort_t* Kbh = Kb + (size_t)bh * S_ * DH_;
  const ushort_t* Vbh = Vt + (size_t)bh * DH_ * S_;

  auto stage = [&](int buf, int c) {
    const int k0s = c << 6;
    const int row  = tid >> 3;                 // 0..63
    const int slot = tid & 7;
    const int scol = ((slot ^ (row & 7)) * 8);
    async_copy16(Kbh + (size_t)(k0s + row) * DH_ + scol, &Ks[buf][tid * 8]);
    async_copy16(Vbh + (size_t)row * S_ + k0s + scol,    &Vs[buf][tid * 8]);
  };

  bf16x8 qb[2];
  {
    const ushort_t* qptr = Qb + ((size_t)bh * S_ + q0 + l15) * DH_ + quad * 8;
    qb[0] = *(const bf16x8*)(qptr);
    qb[1] = *(const bf16x8*)(qptr + 32);
  }

  f32x4 o_acc[4] = {};
  float m_run = -1e30f, l_run = 0.0f;

  stage(0, 0);                          // prologue

  for (int c = 0; c < nch_max; ++c) {
    const int st = c & 1;
    __syncthreads();                    // drains stage issued last iter
    if (c + 1 < nch_max) stage(st ^ 1, c + 1);
    if (c >= nch_w) continue;           // idle wave (tail chunk)
    const int k0 = c << 6;

    bf16x8 ka[4][2];
    #pragma unroll
    for (int kt = 0; kt < 4; ++kt) {
      const int row = kt * 16 + l15;
      const int bse = row * 64, rx = row & 7;
      ka[kt][0] = *(const bf16x8*)&Ks[st][bse + ((quad ^ rx) * 8)];
      ka[kt][1] = *(const bf16x8*)&Ks[st][bse + (((4 + quad) ^ rx) * 8)];
    }

    f32x4 s_t[4];
    __builtin_amdgcn_s_setprio(1);
    #pragma unroll
    for (int kt = 0; kt < 4; ++kt) {
      f32x4 z = {0.0f, 0.0f, 0.0f, 0.0f};
      z = __builtin_amdgcn_mfma_f32_16x16x32_bf16(ka[kt][0], qb[0], z, 0, 0, 0);
      z = __builtin_amdgcn_mfma_f32_16x16x32_bf16(ka[kt][1], qb[1], z, 0, 0, 0);
      s_t[kt] = z;
    }
    __builtin_amdgcn_s_setprio(0);

    if (c == nch_w - 1) {               // diagonal chunk: causal mask
      const int query = q0 + l15;
      #pragma unroll
      for (int kt = 0; kt < 4; ++kt)
        #pragma unroll
        for (int r = 0; r < 4; ++r)
          if (k0 + kt * 16 + quad * 4 + r > query) s_t[kt][r] = -1e30f;
    }

    {
      float mx = -1e30f;
      #pragma unroll
      for (int kt = 0; kt < 4; ++kt)
        #pragma unroll
        for (int r = 0; r < 4; ++r) mx = fmaxf(mx, s_t[kt][r]);
      mx = fmaxf(mx, __shfl_xor(mx, 16, 64));
      mx = fmaxf(mx, __shfl_xor(mx, 32, 64));
      // T13 defer-max: skip rescale while max grows < 8 (P bounded by 2^8).
      if (!__all(mx <= m_run + 8.0f)) {
        const float m_new = fmaxf(m_run, mx);
        const float alpha = exp2_fast(m_run - m_new);
        l_run *= alpha;
        #pragma unroll
        for (int mt = 0; mt < 4; ++mt)
          #pragma unroll
          for (int r = 0; r < 4; ++r) o_acc[mt][r] *= alpha;
        m_run = m_new;
      }
      float rs = 0.0f;
      #pragma unroll
      for (int kt = 0; kt < 4; ++kt)
        #pragma unroll
        for (int r = 0; r < 4; ++r) {
          const float e = exp2_fast(s_t[kt][r] - m_run);
          s_t[kt][r] = e;
          rs += e;
        }
      rs += __shfl_xor(rs, 16, 64);
      rs += __shfl_xor(rs, 32, 64);
      l_run += rs;
    }

    bf16x8 va[4][2];
    #pragma unroll
    for (int mt = 0; mt < 4; ++mt) {
      const int row = mt * 16 + l15;    // dh
      const int bse = row * 64, rx = row & 7;
      va[mt][0] = *(const bf16x8*)&Vs[st][bse + ((quad ^ rx) * 8)];
      va[mt][1] = *(const bf16x8*)&Vs[st][bse + (((4 + quad) ^ rx) * 8)];
    }

    {
      ushort_t* Pw = &Plds[wave][0];
      #pragma unroll
      for (int kt = 0; kt < 4; ++kt) {
        u32x2 wpair;
        wpair[0] = (unsigned)f2bf(s_t[kt][0]) | ((unsigned)f2bf(s_t[kt][1]) << 16);
        wpair[1] = (unsigned)f2bf(s_t[kt][2]) | ((unsigned)f2bf(s_t[kt][3]) << 16);
        *(u32x2*)&Pw[l15 * PPAD + kt * 16 + quad * 4] = wpair;
      }
      asm volatile("s_waitcnt lgkmcnt(0)" ::: "memory");
      const bf16x8 pb0 = *(const bf16x8*)&Pw[l15 * PPAD + quad * 8];
      const bf16x8 pb1 = *(const bf16x8*)&Pw[l15 * PPAD + 32 + quad * 8];
      __builtin_amdgcn_s_setprio(1);
      #pragma unroll
      for (int mt = 0; mt < 4; ++mt) {
        o_acc[mt] = __builtin_amdgcn_mfma_f32_16x16x32_bf16(va[mt][0], pb0, o_acc[mt], 0, 0, 0);
        o_acc[mt] = __builtin_amdgcn_mfma_f32_16x16x32_bf16(va[mt][1], pb1, o_acc[mt], 0, 0, 0);
      }
      __builtin_amdgcn_s_setprio(0);
    }
  }

  {
    const float inv = 1.0f / l_run;
    #pragma unroll
    for (int mt = 0; mt < 4; ++mt) {
      u16x4 pk;
      #pragma unroll
      for (int r = 0; r < 4; ++r) pk[r] = f2bf(o_acc[mt][r] * inv);
      *(u16x4*)&O[(((size_t)b * S_ + q0 + l15) * H_ + h) * DH_ + mt * 16 + quad * 4] = pk;
    }
  }
}

// ---------------------------------------------------------------------------
extern "C" void kernel_launch(void* const* d_in, const int* in_sizes, int n_in,
                              void* d_out, int out_size, void* d_ws, size_t ws_size,
                              hipStream_t stream) {
  const float* x       = (const float*)d_in[0];
  const float* rot_cos = (const float*)d_in[1];
  const float* rot_sin = (const float*)d_in[2];
  const float* ln1_w   = (const float*)d_in[3];
  const float* w_qkv   = (const float*)d_in[4];
  const float* w_out   = (const float*)d_in[5];
  const float* ln2_w   = (const float*)d_in[6];
  const float* w_mlp1  = (const float*)d_in[7];
  const float* b_mlp1  = (const float*)d_in[8];
  const float* w_mlp2  = (const float*)d_in[9];
  const float* b_mlp2  = (const float*)d_in[10];
  float* out = (float*)d_out;

  char* wsb = (char*)d_ws;
  const size_t MB = 1u << 20;
  ushort_t* h1_bf  = (ushort_t*)(wsb + 0 * MB);    // 8 MB  (reused as h2)
  ushort_t* q_bf   = (ushort_t*)(wsb + 32 * MB);   // 8 MB
  ushort_t* k_bf   = (ushort_t*)(wsb + 40 * MB);   // 8 MB
  ushort_t* v_t    = (ushort_t*)(wsb + 48 * MB);   // 8 MB (B,H,Dh,S)
  ushort_t* o_bf   = (ushort_t*)(wsb + 56 * MB);   // 8 MB
  float*    x2     = (float*)   (wsb + 64 * MB);   // 16 MB
  ushort_t* u_bf   = (ushort_t*)(wsb + 80 * MB);   // 32 MB
  ushort_t* wq_bf  = (ushort_t*)(wsb + 112 * MB);  // 6 MB
  ushort_t* wo_bf  = (ushort_t*)(wsb + 118 * MB);  // 2 MB
  ushort_t* w1_bf  = (ushort_t*)(wsb + 120 * MB);  // 8 MB
  ushort_t* w2_bf  = (ushort_t*)(wsb + 128 * MB);  // 8 MB -> 136 MB total
  (void)ws_size; (void)in_sizes; (void)n_in; (void)out_size;

  dim3 b256(256);

  // 0) weights -> bf16
  cast_w_kernel<<<dim3(4096, 4), b256, 0, stream>>>(
      w_qkv, wq_bf, 3 * D_ * D_, w_out, wo_bf, D_ * D_,
      w_mlp1, w1_bf, MLP_ * D_, w_mlp2, w2_bf, MLP_ * D_);
  // 1) h1 = LN(x) * ln1_w -> bf16
  ln_kernel<<<dim3(ROWS_), b256, 0, stream>>>(x, ln1_w, h1_bf);
  // 2) qkv = h1 @ w_qkv^T with FUSED rope: q -> q_bf (scaled), k -> k_bf,
  //    V -> v_t via LDS-transpose (coalesced along S).
  gemm_bt<0, 1, 1><<<dim3(768), b256, 0, stream>>>(
      h1_bf, wq_bf, nullptr, nullptr, nullptr, v_t,
      rot_cos, rot_sin, q_bf, k_bf, ROWS_, 3 * D_, D_, 16, 6, 4);
  // 3) block-cooperative flash attention (8 waves x 16 rows) -> o bf16
  attn_kernel<<<dim3(512), dim3(512), 0, stream>>>(q_bf, k_bf, v_t, o_bf);
  // 4) x2 = x + o @ w_out^T -> fp32
  gemm64_bt<4, 0><<<dim3(512), dim3(512), 0, stream>>>(
      o_bf, wo_bf, nullptr, x, x2, ROWS_, D_, D_, 16, 4, 2);
  // 5) h2 = LN(x2) * ln2_w -> bf16
  ln_kernel<<<dim3(ROWS_), b256, 0, stream>>>(x2, ln2_w, h1_bf);
  // 6) u = gelu(h2 @ w_mlp1^T + b1) -> bf16
  gemm_bt<3, 1, 0><<<dim3(1024), b256, 0, stream>>>(
      h1_bf, w1_bf, b_mlp1, nullptr, u_bf, nullptr,
      nullptr, nullptr, nullptr, nullptr, ROWS_, MLP_, D_, 16, 8, 4);
  // 7) out = x2 + u @ w_mlp2^T + b2 -> fp32
  gemm64_bt<5, 0><<<dim3(512), dim3(512), 0, stream>>>(
      u_bf, w2_bf, b_mlp2, x2, out, ROWS_, D_, MLP_, 16, 4, 2);
}